// Round 5
// baseline (134.961 us; speedup 1.0000x reference)
//
#include <hip/hip_runtime.h>

#define NPTS 131072

#define FRAG0_OFF    0
#define FRAG0_BYTES  4096
#define FRAGH_OFF    4096
#define HLAYER_BYTES 32768
#define FRAGH_BYTES  (3 * HLAYER_BYTES)
#define WCHUNKS      100                         // (FRAG0+FRAGH)/1024
#define BIAS_OFF     (FRAGH_OFF + FRAGH_BYTES)   // 102400
#define BIAS_BYTES   2048
#define WO_OFF       (BIAS_OFF + BIAS_BYTES)     // 104448
#define WOBO_BYTES   528                          // 128 f32 Wo + bo + pad
#define MLP_BYTES    (WO_OFF + WOBO_BYTES)       // dp at 0, ic at MLP_BYTES

typedef _Float16 f16;
typedef __attribute__((ext_vector_type(8)))  _Float16 f16x8;
typedef __attribute__((ext_vector_type(16))) float    f32x16;

#define C2LOG2E 2.8853900817779268f   // 2*log2(e)

__device__ __forceinline__ float tanh_f(float x){
  float e = __builtin_amdgcn_exp2f(x * C2LOG2E);
  return 1.0f - 2.0f * __builtin_amdgcn_rcpf(e + 1.0f);
}

__device__ __forceinline__ void gl_lds16(const void* g, void* l){
  __builtin_amdgcn_global_load_lds(
      (const __attribute__((address_space(1))) void*)g,
      (__attribute__((address_space(3))) void*)l, 16, 0, 0);
}

// ---------------- weight packing (layout unchanged) ----------------
__global__ void pack_weights(
    const float* __restrict__ dpW0, const float* __restrict__ dpb0,
    const float* __restrict__ dpWh, const float* __restrict__ dpbh,
    const float* __restrict__ dpWo, const float* __restrict__ dpbo,
    const float* __restrict__ icW0, const float* __restrict__ icb0,
    const float* __restrict__ icWh, const float* __restrict__ icbh,
    const float* __restrict__ icWo, const float* __restrict__ icbo,
    unsigned char* __restrict__ ws)
{
  int tid = blockIdx.x * blockDim.x + threadIdx.x;
  int nth = gridDim.x * blockDim.x;
  for (int m = 0; m < 2; ++m){
    const float* W0 = m ? icW0 : dpW0;
    const float* Wh = m ? icWh : dpWh;
    const float* b0 = m ? icb0 : dpb0;
    const float* bh = m ? icbh : dpbh;
    const float* Wo = m ? icWo : dpWo;
    const float* bo = m ? icbo : dpbo;
    const int indim = m ? 5 : 6;
    unsigned char* base = ws + m * MLP_BYTES;

    f16* dstF0 = (f16*)(base + FRAG0_OFF);
    for (int idx = tid; idx < 2048; idx += nth){
      int e    = idx & 7;
      int lane = (idx >> 3) & 63;
      int jt   = idx >> 9;
      int j = 32*jt + (lane & 31);
      int k = 8*(lane >> 5) + e;
      float v = (k < indim) ? W0[k*128 + j] : 0.0f;
      dstF0[idx] = (f16)v;
    }
    f16* dstFH = (f16*)(base + FRAGH_OFF);
    for (int idx = tid; idx < 3*16384; idx += nth){
      int layer = idx / 16384;
      int q     = idx & 16383;
      int e    = q & 7;
      int lane = (q >> 3) & 63;
      int f    = q >> 9;            // f = jt*8 + s
      int jt = f >> 3, s = f & 7;
      int j = 32*jt + (lane & 31);
      int k = 16*s + 8*(lane >> 5) + e;
      int row = (k & ~12) | ((k & 4) << 1) | ((k & 8) >> 1); // swap bits 2,3
      float v = Wh[(layer*128 + row)*128 + j];
      dstFH[idx] = (f16)v;
    }
    float* dstB = (float*)(base + BIAS_OFF);
    for (int idx = tid; idx < 512; idx += nth)
      dstB[idx] = (idx < 128) ? b0[idx] : bh[idx - 128];
    float* dstW = (float*)(base + WO_OFF);
    for (int idx = tid; idx < 128; idx += nth) dstW[idx] = Wo[idx];
    if (tid == 0) dstW[128] = bo[0];
  }
}

// ---------------- main fused kernel ----------------
__device__ __forceinline__ f32x16 load_bias16(const float* bp){
  float4 q0 = *(const float4*)(bp +  0);
  float4 q1 = *(const float4*)(bp +  8);
  float4 q2 = *(const float4*)(bp + 16);
  float4 q3 = *(const float4*)(bp + 24);
  f32x16 a;
  a[0]=q0.x;  a[1]=q0.y;  a[2]=q0.z;  a[3]=q0.w;
  a[4]=q1.x;  a[5]=q1.y;  a[6]=q1.z;  a[7]=q1.w;
  a[8]=q2.x;  a[9]=q2.y;  a[10]=q2.z; a[11]=q2.w;
  a[12]=q3.x; a[13]=q3.y; a[14]=q3.z; a[15]=q3.w;
  return a;
}

// 256 blocks x 1024 threads. Blocks 0..191: dp, node = blockIdx>>6 (uniform
// per block). Blocks 192..255: ic (node==3). Each block: stage whole MLP to
// LDS once, then 4 units x 512 points, no further barriers/staging.
__global__ __launch_bounds__(1024) void node_main(
    const float* __restrict__ tx,
    const unsigned char* __restrict__ ws,
    float* __restrict__ out)
{
  __shared__ __align__(16) unsigned char sW[FRAG0_BYTES + FRAGH_BYTES]; // 100KB
  __shared__ __align__(16) float sBias[512];
  __shared__ __align__(16) float sWo[136];

  const int tid  = threadIdx.x;
  const int wave = tid >> 6;
  const int lane = tid & 63;
  const int p32  = lane & 31;
  const int hi   = lane >> 5;
  const int node = blockIdx.x >> 6;            // 0,1,2 = dp GL nodes; 3 = ic
  const unsigned char* mb = ws + (node == 3 ? MLP_BYTES : 0);

  // ---- one-time staging of the whole MLP ----
  for (int c = wave; c < WCHUNKS; c += 16)
    gl_lds16(mb + c*1024 + lane*16, sW + c*1024);
  for (int i = tid; i < 128; i += 1024)
    ((uint4*)sBias)[i] = ((const uint4*)(mb + BIAS_OFF))[i];
  for (int i = tid; i < 33; i += 1024)
    ((uint4*)sWo)[i] = ((const uint4*)(mb + WO_OFF))[i];
  __syncthreads();

  const float gn = (node == 0) ? -0.7745966692414834f :
                   (node == 2) ?  0.7745966692414834f : 0.0f;
  const float wq = (node == 1) ? 0.8888888888888889f : 0.5555555555555556f;

  #pragma unroll 1
  for (int u2 = 0; u2 < 4; ++u2){
    const int batch = (blockIdx.x & 63) * 4 + u2;   // 0..255
    const int p = batch * 512 + wave * 32 + p32;

    float4 c = ((const float4*)tx)[p];
    float x = c.y, y = c.z, z = c.w;
    float xy = x*x + y*y;
    float r    = sqrtf(xy + z*z + 1e-8f);
    float rho  = sqrtf(xy + 1e-8f);
    float rin  = __builtin_amdgcn_rcpf(r);
    float rhin = __builtin_amdgcn_rcpf(rho);
    float u    = r * __builtin_amdgcn_rcpf(1.0f + r);
    float cth  = z * rin;
    float sth  = rho * rin;
    float cph  = x * rhin;
    float sph  = y * rhin;
    float th   = 0.5f * c.x;     // a = t/2 (t0 = 0)

    // input B-frag: k-slot = feature index (hi half = zero padding)
    f16x8 b0f;
    #pragma unroll
    for (int e = 0; e < 8; ++e) b0f[e] = (f16)0.0f;
    if (hi == 0){
      if (node == 3){
        b0f[0]=(f16)u;   b0f[1]=(f16)cth; b0f[2]=(f16)sth;
        b0f[3]=(f16)cph; b0f[4]=(f16)sph;
      } else {
        float ts = th * (1.0f + gn);
        b0f[0]=(f16)ts;  b0f[1]=(f16)u;   b0f[2]=(f16)cth;
        b0f[3]=(f16)sth; b0f[4]=(f16)cph; b0f[5]=(f16)sph;
      }
    }

    f32x16 acc[4];
    // ---- input layer (bias as MFMA C-in) ----
    {
      const f16x8* fr = (const f16x8*)sW;
      #pragma unroll
      for (int jt = 0; jt < 4; ++jt)
        acc[jt] = __builtin_amdgcn_mfma_f32_32x32x16_f16(
                    fr[jt*64 + lane], b0f,
                    load_bias16(&sBias[32*jt + 4*hi]), 0,0,0);
    }

    // ---- 3 hidden layers, weights resident in LDS ----
    #pragma unroll 1
    for (int L = 0; L < 3; ++L){
      union { f16x8 v; unsigned uu[4]; } bf[8];
      #pragma unroll
      for (int jt = 0; jt < 4; ++jt)
        #pragma unroll
        for (int cq = 0; cq < 2; ++cq)
          #pragma unroll
          for (int e = 0; e < 4; ++e){
            float t0 = tanh_f(acc[jt][8*cq + 2*e]);
            float t1 = tanh_f(acc[jt][8*cq + 2*e + 1]);
            auto pk = __builtin_amdgcn_cvt_pkrtz(t0, t1);
            bf[2*jt + cq].uu[e] = __builtin_bit_cast(unsigned, pk);
          }
      const f16x8* fh = (const f16x8*)(sW + FRAGH_OFF + L*HLAYER_BYTES);
      #pragma unroll
      for (int jt = 0; jt < 4; ++jt){
        f32x16 t = load_bias16(&sBias[(L+1)*128 + 32*jt + 4*hi]);
        #pragma unroll
        for (int s = 0; s < 8; ++s)
          t = __builtin_amdgcn_mfma_f32_32x32x16_f16(
                fh[(jt*8 + s)*64 + lane], bf[s].v, t, 0,0,0);
        acc[jt] = t;
      }
    }

    // ---- output layer: v = sum_j tanh(h_j) * Wo[j] + bo ----
    float v = 0.0f;
    #pragma unroll
    for (int jt = 0; jt < 4; ++jt){
      const float* wp = &sWo[32*jt + 4*hi];
      float4 q0 = *(const float4*)(wp +  0);
      float4 q1 = *(const float4*)(wp +  8);
      float4 q2 = *(const float4*)(wp + 16);
      float4 q3 = *(const float4*)(wp + 24);
      f32x16 A = acc[jt];
      v += tanh_f(A[0])*q0.x  + tanh_f(A[1])*q0.y
         + tanh_f(A[2])*q0.z  + tanh_f(A[3])*q0.w
         + tanh_f(A[4])*q1.x  + tanh_f(A[5])*q1.y
         + tanh_f(A[6])*q1.z  + tanh_f(A[7])*q1.w
         + tanh_f(A[8])*q2.x  + tanh_f(A[9])*q2.y
         + tanh_f(A[10])*q2.z + tanh_f(A[11])*q2.w
         + tanh_f(A[12])*q3.x + tanh_f(A[13])*q3.y
         + tanh_f(A[14])*q3.z + tanh_f(A[15])*q3.w;
    }
    v += __shfl_xor(v, 32);                  // combine the two row-halves
    v += sWo[128];                           // bo
    const float contrib = (node == 3) ? v : th * wq * v;
    if (hi == 0) unsafeAtomicAdd(&out[p], contrib);
  }
}

extern "C" void kernel_launch(void* const* d_in, const int* in_sizes, int n_in,
                              void* d_out, int out_size, void* d_ws, size_t ws_size,
                              hipStream_t stream)
{
  const float* tx = (const float*)d_in[0];
  hipMemsetAsync(d_out, 0, (size_t)out_size * sizeof(float), stream);
  pack_weights<<<64, 256, 0, stream>>>(
      (const float*)d_in[1],  (const float*)d_in[2],  (const float*)d_in[3],
      (const float*)d_in[4],  (const float*)d_in[5],  (const float*)d_in[6],
      (const float*)d_in[7],  (const float*)d_in[8],  (const float*)d_in[9],
      (const float*)d_in[10], (const float*)d_in[11], (const float*)d_in[12],
      (unsigned char*)d_ws);
  node_main<<<256, 1024, 0, stream>>>(tx, (const unsigned char*)d_ws, (float*)d_out);
}

// Round 6
// 86.943 us; speedup vs baseline: 1.5523x; 1.5523x over previous
//
#include <hip/hip_runtime.h>

#define NPTS 131072

#define FRAG0_OFF    0
#define FRAG0_BYTES  4096
#define FRAGH_OFF    4096
#define HLAYER_BYTES 32768
#define FRAGH_BYTES  (3 * HLAYER_BYTES)
#define WCHUNKS      100                         // (FRAG0+FRAGH)/1024
#define BIAS_OFF     (FRAGH_OFF + FRAGH_BYTES)   // 102400
#define BIAS_BYTES   2048
#define WO_OFF       (BIAS_OFF + BIAS_BYTES)     // 104448
#define WOBO_BYTES   528                          // 128 f32 Wo + bo + pad
#define MLP_BYTES    (WO_OFF + WOBO_BYTES)       // dp at 0, ic at MLP_BYTES

typedef _Float16 f16;
typedef __attribute__((ext_vector_type(8)))  _Float16 f16x8;
typedef __attribute__((ext_vector_type(16))) float    f32x16;

#define C2LOG2E 2.8853900817779268f   // 2*log2(e)

__device__ __forceinline__ float tanh_f(float x){
  float e = __builtin_amdgcn_exp2f(x * C2LOG2E);
  return 1.0f - 2.0f * __builtin_amdgcn_rcpf(e + 1.0f);
}

__device__ __forceinline__ void gl_lds16(const void* g, void* l){
  __builtin_amdgcn_global_load_lds(
      (const __attribute__((address_space(1))) void*)g,
      (__attribute__((address_space(3))) void*)l, 16, 0, 0);
}

// ---------------- weight packing (layout unchanged) ----------------
__global__ void pack_weights(
    const float* __restrict__ dpW0, const float* __restrict__ dpb0,
    const float* __restrict__ dpWh, const float* __restrict__ dpbh,
    const float* __restrict__ dpWo, const float* __restrict__ dpbo,
    const float* __restrict__ icW0, const float* __restrict__ icb0,
    const float* __restrict__ icWh, const float* __restrict__ icbh,
    const float* __restrict__ icWo, const float* __restrict__ icbo,
    unsigned char* __restrict__ ws)
{
  int tid = blockIdx.x * blockDim.x + threadIdx.x;
  int nth = gridDim.x * blockDim.x;
  for (int m = 0; m < 2; ++m){
    const float* W0 = m ? icW0 : dpW0;
    const float* Wh = m ? icWh : dpWh;
    const float* b0 = m ? icb0 : dpb0;
    const float* bh = m ? icbh : dpbh;
    const float* Wo = m ? icWo : dpWo;
    const float* bo = m ? icbo : dpbo;
    const int indim = m ? 5 : 6;
    unsigned char* base = ws + m * MLP_BYTES;

    f16* dstF0 = (f16*)(base + FRAG0_OFF);
    for (int idx = tid; idx < 2048; idx += nth){
      int e    = idx & 7;
      int lane = (idx >> 3) & 63;
      int jt   = idx >> 9;
      int j = 32*jt + (lane & 31);
      int k = 8*(lane >> 5) + e;
      float v = (k < indim) ? W0[k*128 + j] : 0.0f;
      dstF0[idx] = (f16)v;
    }
    f16* dstFH = (f16*)(base + FRAGH_OFF);
    for (int idx = tid; idx < 3*16384; idx += nth){
      int layer = idx / 16384;
      int q     = idx & 16383;
      int e    = q & 7;
      int lane = (q >> 3) & 63;
      int f    = q >> 9;            // f = jt*8 + s
      int jt = f >> 3, s = f & 7;
      int j = 32*jt + (lane & 31);
      int k = 16*s + 8*(lane >> 5) + e;
      int row = (k & ~12) | ((k & 4) << 1) | ((k & 8) >> 1); // swap bits 2,3
      float v = Wh[(layer*128 + row)*128 + j];
      dstFH[idx] = (f16)v;
    }
    float* dstB = (float*)(base + BIAS_OFF);
    for (int idx = tid; idx < 512; idx += nth)
      dstB[idx] = (idx < 128) ? b0[idx] : bh[idx - 128];
    float* dstW = (float*)(base + WO_OFF);
    for (int idx = tid; idx < 128; idx += nth) dstW[idx] = Wo[idx];
    if (tid == 0) dstW[128] = bo[0];
  }
}

// ---------------- main fused kernel ----------------
__device__ __forceinline__ f32x16 load_bias16(const float* bp){
  float4 q0 = *(const float4*)(bp +  0);
  float4 q1 = *(const float4*)(bp +  8);
  float4 q2 = *(const float4*)(bp + 16);
  float4 q3 = *(const float4*)(bp + 24);
  f32x16 a;
  a[0]=q0.x;  a[1]=q0.y;  a[2]=q0.z;  a[3]=q0.w;
  a[4]=q1.x;  a[5]=q1.y;  a[6]=q1.z;  a[7]=q1.w;
  a[8]=q2.x;  a[9]=q2.y;  a[10]=q2.z; a[11]=q2.w;
  a[12]=q3.x; a[13]=q3.y; a[14]=q3.z; a[15]=q3.w;
  return a;
}

// 256 blocks x 512 threads (8 waves). Each block owns 512 consecutive points
// (64 per wave = 2 column-tiles). Stage dp MLP once -> run 3 dp chains
// (vsum in regs) -> restage ic over same LDS -> ic chain -> one final write.
// Each A-frag ds_read feeds 2 MFMAs (2 tiles) => half the LDS traffic.
__global__ __launch_bounds__(512, 2) void node_main(
    const float* __restrict__ tx,
    const unsigned char* __restrict__ ws,
    float* __restrict__ out)
{
  __shared__ __align__(16) unsigned char sW[FRAG0_BYTES + FRAGH_BYTES]; // 100KB
  __shared__ __align__(16) float sBias[512];
  __shared__ __align__(16) float sWo[136];

  const int tid  = threadIdx.x;
  const int wave = tid >> 6;
  const int lane = tid & 63;
  const int p32  = lane & 31;
  const int hi   = lane >> 5;
  const int base = blockIdx.x * 512;

  // ---- spherical features for this lane's two points (tiles ct=0/1) ----
  float u[2], cth[2], sth[2], cph[2], sph[2], th[2];
  #pragma unroll
  for (int ct = 0; ct < 2; ++ct){
    int gp = base + wave*64 + ct*32 + p32;
    float4 c = ((const float4*)tx)[gp];
    float x = c.y, y = c.z, z = c.w;
    float xy = x*x + y*y;
    float r    = sqrtf(xy + z*z + 1e-8f);
    float rho  = sqrtf(xy + 1e-8f);
    float rin  = __builtin_amdgcn_rcpf(r);
    float rhin = __builtin_amdgcn_rcpf(rho);
    u[ct]   = r * __builtin_amdgcn_rcpf(1.0f + r);
    cth[ct] = z * rin;
    sth[ct] = rho * rin;
    cph[ct] = x * rhin;
    sph[ct] = y * rhin;
    th[ct]  = 0.5f * c.x;       // a = t/2 (t0 = 0)
  }

  float vsum[2] = {0.0f, 0.0f};
  f32x16 acc[4][2];

  #pragma unroll 1
  for (int chain = 0; chain < 4; ++chain){   // 0,1,2 = dp GL nodes; 3 = ic
    if (chain == 0 || chain == 3){
      const unsigned char* mb = ws + (chain == 3 ? MLP_BYTES : 0);
      __syncthreads();                       // prior users of sW done
      for (int c = wave; c < WCHUNKS; c += 8)
        gl_lds16(mb + c*1024 + lane*16, sW + c*1024);
      for (int i = tid; i < 128; i += 512)
        ((uint4*)sBias)[i] = ((const uint4*)(mb + BIAS_OFF))[i];
      for (int i = tid; i < 33; i += 512)
        ((uint4*)sWo)[i] = ((const uint4*)(mb + WO_OFF))[i];
      __syncthreads();                       // staging visible
    }

    const float gn = (chain == 0) ? -0.7745966692414834f :
                     (chain == 2) ?  0.7745966692414834f : 0.0f;

    // input B-frags: k-slot = feature index (hi half = zero padding)
    f16x8 b0f[2];
    #pragma unroll
    for (int ct = 0; ct < 2; ++ct){
      #pragma unroll
      for (int e = 0; e < 8; ++e) b0f[ct][e] = (f16)0.0f;
      if (hi == 0){
        if (chain == 3){
          b0f[ct][0]=(f16)u[ct];   b0f[ct][1]=(f16)cth[ct];
          b0f[ct][2]=(f16)sth[ct]; b0f[ct][3]=(f16)cph[ct];
          b0f[ct][4]=(f16)sph[ct];
        } else {
          float ts = th[ct] * (1.0f + gn);
          b0f[ct][0]=(f16)ts;      b0f[ct][1]=(f16)u[ct];
          b0f[ct][2]=(f16)cth[ct]; b0f[ct][3]=(f16)sth[ct];
          b0f[ct][4]=(f16)cph[ct]; b0f[ct][5]=(f16)sph[ct];
        }
      }
    }

    // ---- input layer (bias as MFMA C-in); one frag read -> 2 MFMAs ----
    {
      const f16x8* fr = (const f16x8*)sW;
      #pragma unroll
      for (int jt = 0; jt < 4; ++jt){
        f16x8 a = fr[jt*64 + lane];
        f32x16 b = load_bias16(&sBias[32*jt + 4*hi]);
        acc[jt][0] = __builtin_amdgcn_mfma_f32_32x32x16_f16(a, b0f[0], b, 0,0,0);
        acc[jt][1] = __builtin_amdgcn_mfma_f32_32x32x16_f16(a, b0f[1], b, 0,0,0);
      }
    }

    // ---- 3 hidden layers, weights resident in LDS ----
    #pragma unroll 1
    for (int L = 0; L < 3; ++L){
      union { f16x8 v; unsigned uu[4]; } bf[2][8];
      #pragma unroll
      for (int ct = 0; ct < 2; ++ct)
        #pragma unroll
        for (int jt = 0; jt < 4; ++jt)
          #pragma unroll
          for (int cq = 0; cq < 2; ++cq)
            #pragma unroll
            for (int e = 0; e < 4; ++e){
              float t0 = tanh_f(acc[jt][ct][8*cq + 2*e]);
              float t1 = tanh_f(acc[jt][ct][8*cq + 2*e + 1]);
              auto pk = __builtin_amdgcn_cvt_pkrtz(t0, t1);
              bf[ct][2*jt + cq].uu[e] = __builtin_bit_cast(unsigned, pk);
            }
      const f16x8* fh = (const f16x8*)(sW + FRAGH_OFF + L*HLAYER_BYTES);
      #pragma unroll
      for (int jt = 0; jt < 4; ++jt){
        f32x16 b = load_bias16(&sBias[(L+1)*128 + 32*jt + 4*hi]);
        f32x16 t0 = b, t1 = b;
        #pragma unroll
        for (int s = 0; s < 8; ++s){
          f16x8 a = fh[(jt*8 + s)*64 + lane];
          t0 = __builtin_amdgcn_mfma_f32_32x32x16_f16(a, bf[0][s].v, t0, 0,0,0);
          t1 = __builtin_amdgcn_mfma_f32_32x32x16_f16(a, bf[1][s].v, t1, 0,0,0);
        }
        acc[jt][0] = t0;
        acc[jt][1] = t1;
      }
    }

    // ---- output layer: v = sum_j tanh(h_j) * Wo[j] + bo ----
    #pragma unroll
    for (int ct = 0; ct < 2; ++ct){
      float v = 0.0f;
      #pragma unroll
      for (int jt = 0; jt < 4; ++jt){
        const float* wp = &sWo[32*jt + 4*hi];
        float4 q0 = *(const float4*)(wp +  0);
        float4 q1 = *(const float4*)(wp +  8);
        float4 q2 = *(const float4*)(wp + 16);
        float4 q3 = *(const float4*)(wp + 24);
        f32x16 A = acc[jt][ct];
        v += tanh_f(A[0])*q0.x  + tanh_f(A[1])*q0.y
           + tanh_f(A[2])*q0.z  + tanh_f(A[3])*q0.w
           + tanh_f(A[4])*q1.x  + tanh_f(A[5])*q1.y
           + tanh_f(A[6])*q1.z  + tanh_f(A[7])*q1.w
           + tanh_f(A[8])*q2.x  + tanh_f(A[9])*q2.y
           + tanh_f(A[10])*q2.z + tanh_f(A[11])*q2.w
           + tanh_f(A[12])*q3.x + tanh_f(A[13])*q3.y
           + tanh_f(A[14])*q3.z + tanh_f(A[15])*q3.w;
      }
      v += __shfl_xor(v, 32);                // combine the two row-halves
      v += sWo[128];                         // bo
      if (chain == 3){
        if (hi == 0) out[base + wave*64 + ct*32 + p32] = v + vsum[ct];
      } else {
        const float wq = (chain == 1) ? 0.8888888888888889f
                                      : 0.5555555555555556f;
        vsum[ct] = __builtin_fmaf(th[ct] * wq, v, vsum[ct]);
      }
    }
  }
}

extern "C" void kernel_launch(void* const* d_in, const int* in_sizes, int n_in,
                              void* d_out, int out_size, void* d_ws, size_t ws_size,
                              hipStream_t stream)
{
  const float* tx = (const float*)d_in[0];
  pack_weights<<<64, 256, 0, stream>>>(
      (const float*)d_in[1],  (const float*)d_in[2],  (const float*)d_in[3],
      (const float*)d_in[4],  (const float*)d_in[5],  (const float*)d_in[6],
      (const float*)d_in[7],  (const float*)d_in[8],  (const float*)d_in[9],
      (const float*)d_in[10], (const float*)d_in[11], (const float*)d_in[12],
      (unsigned char*)d_ws);
  node_main<<<256, 512, 0, stream>>>(tx, (const unsigned char*)d_ws, (float*)d_out);
}